// Round 7
// baseline (504.411 us; speedup 1.0000x reference)
//
#include <hip/hip_runtime.h>

#define T_STEPS 16
#define H 64
#define S_IN 25
#define A_OUT 4
#define NB 65536
#define UPW 16            // units per thread (H / 4 waves)
#define EPB 64            // batch elements per block (one per lane)

typedef unsigned long long ull;

__device__ __forceinline__ float fmaf_(float a, float b, float c) { return __builtin_fmaf(a, b, c); }

// Transpose W2 (64x64) and W3 (4x64) into workspace so the hot loop reads
// contiguous wave-uniform rows.
__global__ void snn_prep(const float* __restrict__ W2, const float* __restrict__ W3,
                         float* __restrict__ W2T, float* __restrict__ W3T) {
    int i = blockIdx.x * blockDim.x + threadIdx.x;
    if (i < H * H) { int h = i >> 6, k = i & 63; W2T[k * H + h] = W2[h * H + k]; }
    if (i < A_OUT * H) { int a = i >> 6, h = i & 63; W3T[h * A_OUT + a] = W3[a * H + h]; }
}

// R5 structure (lane = batch element; wave owns 16 hidden units of 64 elems;
// 4 waves/SIMD) + two k-loop fixes: (a) mask bits from u32 halves with static
// shifts -> v_bfe+v_cvt (2 VALU/k instead of ~4), (b) 2-row SGPR double-buffer
// prefetch of W2T rows so SMEM latency hides under FMAs.
__global__ __launch_bounds__(256, 4) void snn_main(
    const float* __restrict__ x,
    const float* __restrict__ W1, const float* __restrict__ b1,
    const float* __restrict__ W2T, const float* __restrict__ b2,
    const float* __restrict__ W3T, const float* __restrict__ b3,
    float* __restrict__ out, int* __restrict__ g_pre, int* __restrict__ g_post)
{
#pragma clang fp contract(off)
    __shared__ unsigned int s1buf[2][4][EPB];   // [slot][wave][elem] 16-bit quarter masks
    __shared__ unsigned int s2buf[2][4][EPB];
    __shared__ float m3acc[EPB][8];             // [elem][0..3]=m3, [4..7]=acc
    __shared__ int lds_pre[T_STEPS * H];
    __shared__ int lds_post[T_STEPS * A_OUT];

    for (int i = threadIdx.x; i < T_STEPS * H; i += 256) lds_pre[i] = 0;
    if (threadIdx.x < T_STEPS * A_OUT) lds_post[threadIdx.x] = 0;
    for (int i = threadIdx.x; i < EPB * 8; i += 256) (&m3acc[0][0])[i] = 0.0f;

    const int lane  = threadIdx.x & 63;
    const int wq    = __builtin_amdgcn_readfirstlane(threadIdx.x >> 6);  // wave id 0..3 (SGPR)
    const int hbase = UPW * wq;                                          // this wave's unit range
    const int b     = blockIdx.x * EPB + lane;                           // batch element

    // cur1 for this thread's 16 units (same s-chain as reference)
    float cur1[UPW];
    {
        float xv[S_IN];
        #pragma unroll
        for (int s = 0; s < S_IN; ++s) xv[s] = x[b * S_IN + s];
        #pragma unroll
        for (int j = 0; j < UPW; ++j) {
            int h = hbase + j;
            float acc = 0.0f;
            #pragma unroll
            for (int s = 0; s < S_IN; ++s) acc = fmaf_(xv[s], W1[h * S_IN + s], acc);
            cur1[j] = acc + b1[h];
        }
    }

    float m1[UPW], m2[UPW];
    #pragma unroll
    for (int j = 0; j < UPW; ++j) { m1[j] = 0.0f; m2[j] = 0.0f; }

    // ---- prologue: layer-1 at t=0 ----
    {
        unsigned int s1loc = 0u;
        #pragma unroll
        for (int j = 0; j < UPW; ++j) {
            float m = 0.95f * m1[j];
            m = m + cur1[j];
            bool sp = m > 1.0f;
            m1[j] = sp ? (m - 1.0f) : m;
            s1loc |= (sp ? 1u : 0u) << j;
        }
        s1buf[0][wq][lane] = s1loc;
    }
    __syncthreads();

    float ac_final[A_OUT];   // valid in wave 3 after t=15
    #pragma unroll
    for (int a = 0; a < A_OUT; ++a) ac_final[a] = 0.0f;

    const float* wbase = W2T + hbase;           // wave-uniform -> SGPR rows

    for (int t = 0; t < T_STEPS; ++t) {
        const int slot = t & 1;

        // ---- layer 2: full s1 mask (two u32 halves), exact k-chain ----
        unsigned int p0 = s1buf[slot][0][lane], p1 = s1buf[slot][1][lane];
        unsigned int p2 = s1buf[slot][2][lane], p3 = s1buf[slot][3][lane];
        const unsigned int mlo = p0 | (p1 << 16);
        const unsigned int mhi = p2 | (p3 << 16);

        #pragma unroll
        for (int j = 0; j < UPW; ++j) m2[j] = 0.95f * m2[j];

        float4 wA[4], wB[4];                    // rows k (even/odd) double-buffer
        {
            const float4* p0r = reinterpret_cast<const float4*>(wbase);
            const float4* p1r = reinterpret_cast<const float4*>(wbase + H);
            #pragma unroll
            for (int q = 0; q < 4; ++q) { wA[q] = p0r[q]; wB[q] = p1r[q]; }
        }
        #pragma unroll
        for (int k = 0; k < H; ++k) {           // fully static: bfe shift + parity + half
            const unsigned int word = (k < 32) ? mlo : mhi;        // compile-time select
            const float sf = (float)((word >> (k & 31)) & 1u);     // v_bfe + v_cvt
            float4* wc = (k & 1) ? wB : wA;                        // compile-time select
            #pragma unroll
            for (int q = 0; q < 4; ++q) {
                m2[4*q+0] = fmaf_(sf, wc[q].x, m2[4*q+0]);   // exact: sf in {0,1};
                m2[4*q+1] = fmaf_(sf, wc[q].y, m2[4*q+1]);   // k-ascending chain
                m2[4*q+2] = fmaf_(sf, wc[q].z, m2[4*q+2]);   // identical to R5/ref
                m2[4*q+3] = fmaf_(sf, wc[q].w, m2[4*q+3]);
            }
            if (k + 2 < H) {                    // prefetch row k+2 into retired buffer
                const float4* pn = reinterpret_cast<const float4*>(wbase + (k + 2) * H);
                #pragma unroll
                for (int q = 0; q < 4; ++q) wc[q] = pn[q];
            }
        }

        // ---- layer-2 spikes + pre-counts (this wave's units, all 64 elems) ----
        unsigned int s2loc = 0u;
        int myCnt = 0;
        #pragma unroll
        for (int j = 0; j < UPW; ++j) {
            float m = m2[j] + b2[hbase + j];
            bool sp = m > 1.0f;
            float s2f = sp ? 1.0f : 0.0f;
            m2[j] = m - s2f;
            s2loc |= (sp ? 1u : 0u) << j;
            int cnt = (int)__popcll(__ballot(sp));
            myCnt = (lane == j) ? cnt : myCnt;
        }
        s2buf[slot][wq][lane] = s2loc;
        if (lane < UPW) lds_pre[t * H + hbase + lane] = myCnt;  // single writer per slot

        // ---- layer 1 for t+1 (independent of layer 3) ----
        if (t < T_STEPS - 1) {
            unsigned int s1loc = 0u;
            #pragma unroll
            for (int j = 0; j < UPW; ++j) {
                float m = 0.95f * m1[j];
                m = m + cur1[j];
                bool sp = m > 1.0f;
                m1[j] = sp ? (m - 1.0f) : m;
                s1loc |= (sp ? 1u : 0u) << j;
            }
            s1buf[slot ^ 1][wq][lane] = s1loc;
        }
        __syncthreads();

        // ---- layer 3: rotating duty wave (balances SIMDs), exact h-chain ----
        if (wq == (t & 3)) {
            unsigned int q0 = s2buf[slot][0][lane], q1 = s2buf[slot][1][lane];
            unsigned int q2 = s2buf[slot][2][lane], q3 = s2buf[slot][3][lane];
            ull s2v = (ull)(q0 | (q1 << 16)) | ((ull)(q2 | (q3 << 16)) << 32);
            float m3[A_OUT], ac[A_OUT];
            #pragma unroll
            for (int a = 0; a < A_OUT; ++a) { m3[a] = 0.95f * m3acc[lane][a]; ac[a] = m3acc[lane][4 + a]; }
            for (int h = 0; h < H; ++h) {        // h ascending: exact chain order
                float s2f = (float)((unsigned)s2v & 1u);
                s2v >>= 1;
                const float4 w = *reinterpret_cast<const float4*>(W3T + h * A_OUT); // uniform 16B
                m3[0] = fmaf_(s2f, w.x, m3[0]);
                m3[1] = fmaf_(s2f, w.y, m3[1]);
                m3[2] = fmaf_(s2f, w.z, m3[2]);
                m3[3] = fmaf_(s2f, w.w, m3[3]);
            }
            int myPost = 0;
            #pragma unroll
            for (int a = 0; a < A_OUT; ++a) {
                float m = m3[a] + b3[a];
                bool sp = m > 1.0f;
                float s3f = sp ? 1.0f : 0.0f;
                m3[a] = m - s3f;
                ac[a] = ac[a] + s3f;
                int c = (int)__popcll(__ballot(sp));
                myPost = (lane == a) ? c : myPost;
            }
            if (lane < A_OUT) lds_post[t * A_OUT + lane] = myPost;
            if (t == T_STEPS - 1) {
                float r0 = ac[0] * 0.0625f, r1 = ac[1] * 0.0625f;
                float r2 = ac[2] * 0.0625f, r3 = ac[3] * 0.0625f;
                float mx = fmaxf(fmaxf(r0, r1), fmaxf(r2, r3));
                float e0 = expf(r0 - mx), e1 = expf(r1 - mx);
                float e2 = expf(r2 - mx), e3 = expf(r3 - mx);
                float s = ((e0 + e1) + e2) + e3;
                reinterpret_cast<float4*>(out)[blockIdx.x * EPB + lane] =
                    make_float4(e0 / s, e1 / s, e2 / s, e3 / s);
            } else {
                #pragma unroll
                for (int a = 0; a < A_OUT; ++a) { m3acc[lane][a] = m3[a]; m3acc[lane][4 + a] = ac[a]; }
            }
        }
    }

    __syncthreads();
    for (int i = threadIdx.x; i < T_STEPS * H; i += 256) atomicAdd(&g_pre[i], lds_pre[i]);
    if (threadIdx.x < T_STEPS * A_OUT) atomicAdd(&g_post[threadIdx.x], lds_post[threadIdx.x]);
}

// elig_t = 0.95*elig_{t-1} + (A_PLUS-A_MINUS) * outer(post_t, pre_t); exact counts/B.
__global__ void snn_elig(const int* __restrict__ g_pre, const int* __restrict__ g_post,
                         const float* __restrict__ elig0, float* __restrict__ out) {
#pragma clang fp contract(off)
    int i = threadIdx.x;                 // 256 = A_OUT * H
    int a = i >> 6, h = i & 63;
    float e = elig0[i];
    const float invB = 1.0f / 65536.0f;
    for (int t = 0; t < T_STEPS; ++t) {
        float pre  = (float)g_pre[t * H + h] * invB;
        float post = (float)g_post[t * A_OUT + a] * invB;
        e = 0.95f * e + (-0.002f) * (post * pre);
    }
    out[NB * A_OUT + i] = e;
}

extern "C" void kernel_launch(void* const* d_in, const int* in_sizes, int n_in,
                              void* d_out, int out_size, void* d_ws, size_t ws_size,
                              hipStream_t stream) {
    const float* x     = (const float*)d_in[0];
    const float* W1    = (const float*)d_in[1];
    const float* b1    = (const float*)d_in[2];
    const float* W2    = (const float*)d_in[3];
    const float* b2    = (const float*)d_in[4];
    const float* W3    = (const float*)d_in[5];
    const float* b3    = (const float*)d_in[6];
    const float* elig0 = (const float*)d_in[7];
    float* out = (float*)d_out;

    char* ws = (char*)d_ws;
    int*   g_pre  = (int*)(ws);                    // 1024 ints
    int*   g_post = (int*)(ws + 4096);             // 64 ints
    float* W2T    = (float*)(ws + 8192);           // 4096 floats
    float* W3T    = (float*)(ws + 8192 + 16384);   // 256 floats

    (void)hipMemsetAsync(ws, 0, 4096 + 256, stream);  // zero count accumulators every launch
    snn_prep<<<17, 256, 0, stream>>>(W2, W3, W2T, W3T);
    snn_main<<<NB / EPB, 256, 0, stream>>>(x, W1, b1, W2T, b2, W3T, b3, out, g_pre, g_post);
    snn_elig<<<1, 256, 0, stream>>>(g_pre, g_post, elig0, out);
}

// Round 8
// 185.766 us; speedup vs baseline: 2.7153x; 2.7153x over previous
//
#include <hip/hip_runtime.h>

#define T_STEPS 16
#define H 64
#define S_IN 25
#define A_OUT 4
#define NB 65536
#define UPW 8             // units per thread (H / 8 waves)
#define WPB 8             // waves per block
#define EPB 64            // batch elements per block (one per lane)

typedef unsigned long long ull;

__device__ __forceinline__ float fmaf_(float a, float b, float c) { return __builtin_fmaf(a, b, c); }

// Transpose W2 (64x64) and W3 (4x64) into workspace so the hot loop reads
// contiguous wave-uniform rows (scalar s_load path, K$-cached).
__global__ void snn_prep(const float* __restrict__ W2, const float* __restrict__ W3,
                         float* __restrict__ W2T, float* __restrict__ W3T) {
    int i = blockIdx.x * blockDim.x + threadIdx.x;
    if (i < H * H) { int h = i >> 6, k = i & 63; W2T[k * H + h] = W2[h * H + k]; }
    if (i < A_OUT * H) { int a = i >> 6, h = i & 63; W3T[h * A_OUT + a] = W3[a * H + h]; }
}

// R5 structure scaled to 8 waves/SIMD: lane = batch element, 8 waves/block each
// owning 8 hidden units, grid 1024 x 512thr -> 32 waves/CU. Weights stay on the
// scalar path (wave-uniform pointers -> s_load; R7 proved VGPR buffering of
// them is catastrophic). TLP, not ILP, hides the per-k SMEM latency.
__global__ __launch_bounds__(512, 8) void snn_main(
    const float* __restrict__ x,
    const float* __restrict__ W1, const float* __restrict__ b1,
    const float* __restrict__ W2T, const float* __restrict__ b2,
    const float* __restrict__ W3T, const float* __restrict__ b3,
    float* __restrict__ out, int* __restrict__ g_pre, int* __restrict__ g_post)
{
#pragma clang fp contract(off)
    __shared__ unsigned int s1buf[2][WPB][EPB]; // [slot][wave][elem] 8-bit partial masks
    __shared__ unsigned int s2buf[2][WPB][EPB];
    __shared__ float m3acc[EPB][8];             // [elem][0..3]=m3, [4..7]=acc
    __shared__ int lds_pre[T_STEPS * H];
    __shared__ int lds_post[T_STEPS * A_OUT];

    for (int i = threadIdx.x; i < T_STEPS * H; i += 512) lds_pre[i] = 0;
    if (threadIdx.x < T_STEPS * A_OUT) lds_post[threadIdx.x] = 0;
    if (threadIdx.x < EPB * 8) (&m3acc[0][0])[threadIdx.x] = 0.0f;

    const int lane  = threadIdx.x & 63;
    const int wq    = __builtin_amdgcn_readfirstlane(threadIdx.x >> 6);  // wave 0..7 (SGPR)
    const int hbase = UPW * wq;                                          // this wave's unit range
    const int b     = blockIdx.x * EPB + lane;                           // batch element

    // cur1 for this thread's 8 units (same s-chain as reference)
    float cur1[UPW];
    {
        float xv[S_IN];
        #pragma unroll
        for (int s = 0; s < S_IN; ++s) xv[s] = x[b * S_IN + s];
        #pragma unroll
        for (int j = 0; j < UPW; ++j) {
            int h = hbase + j;                  // wave-uniform -> W1 row via s_load
            float acc = 0.0f;
            #pragma unroll
            for (int s = 0; s < S_IN; ++s) acc = fmaf_(xv[s], W1[h * S_IN + s], acc);
            cur1[j] = acc + b1[h];
        }
    }

    float m1[UPW], m2[UPW];
    #pragma unroll
    for (int j = 0; j < UPW; ++j) { m1[j] = 0.0f; m2[j] = 0.0f; }

    // ---- prologue: layer-1 at t=0 ----
    {
        unsigned int s1loc = 0u;
        #pragma unroll
        for (int j = 0; j < UPW; ++j) {
            float m = 0.95f * m1[j];
            m = m + cur1[j];
            bool sp = m > 1.0f;
            m1[j] = sp ? (m - 1.0f) : m;
            s1loc |= (sp ? 1u : 0u) << j;
        }
        s1buf[0][wq][lane] = s1loc;
    }
    __syncthreads();

    for (int t = 0; t < T_STEPS; ++t) {
        const int slot = t & 1;

        // ---- layer 2: assemble full 64-bit s1 mask as two u32 words ----
        unsigned int p0 = s1buf[slot][0][lane], p1 = s1buf[slot][1][lane];
        unsigned int p2 = s1buf[slot][2][lane], p3 = s1buf[slot][3][lane];
        unsigned int p4 = s1buf[slot][4][lane], p5 = s1buf[slot][5][lane];
        unsigned int p6 = s1buf[slot][6][lane], p7 = s1buf[slot][7][lane];
        const unsigned int mlo = p0 | (p1 << 8) | (p2 << 16) | (p3 << 24);
        const unsigned int mhi = p4 | (p5 << 8) | (p6 << 16) | (p7 << 24);

        #pragma unroll
        for (int j = 0; j < UPW; ++j) m2[j] = 0.95f * m2[j];

        // exact ascending-k chain; weights via wave-uniform s_load (K$)
        #pragma unroll 4
        for (int k = 0; k < 32; ++k) {
            const float sf = (float)((mlo >> k) & 1u);        // v_bfe + v_cvt
            const float* wr = W2T + k * H + hbase;
            #pragma unroll
            for (int j = 0; j < UPW; ++j) m2[j] = fmaf_(sf, wr[j], m2[j]);
        }
        #pragma unroll 4
        for (int k = 0; k < 32; ++k) {
            const float sf = (float)((mhi >> k) & 1u);
            const float* wr = W2T + (k + 32) * H + hbase;
            #pragma unroll
            for (int j = 0; j < UPW; ++j) m2[j] = fmaf_(sf, wr[j], m2[j]);
        }

        // ---- layer-2 spikes + pre-counts (this wave's 8 units, all 64 elems) ----
        unsigned int s2loc = 0u;
        int myCnt = 0;
        #pragma unroll
        for (int j = 0; j < UPW; ++j) {
            float m = m2[j] + b2[hbase + j];
            bool sp = m > 1.0f;
            float s2f = sp ? 1.0f : 0.0f;
            m2[j] = m - s2f;
            s2loc |= (sp ? 1u : 0u) << j;
            int cnt = (int)__popcll(__ballot(sp));
            myCnt = (lane == j) ? cnt : myCnt;
        }
        s2buf[slot][wq][lane] = s2loc;
        if (lane < UPW) lds_pre[t * H + hbase + lane] = myCnt;  // single writer per h

        // ---- layer 1 for t+1 (independent of layer 3) ----
        if (t < T_STEPS - 1) {
            unsigned int s1loc = 0u;
            #pragma unroll
            for (int j = 0; j < UPW; ++j) {
                float m = 0.95f * m1[j];
                m = m + cur1[j];
                bool sp = m > 1.0f;
                m1[j] = sp ? (m - 1.0f) : m;
                s1loc |= (sp ? 1u : 0u) << j;
            }
            s1buf[slot ^ 1][wq][lane] = s1loc;
        }
        __syncthreads();

        // ---- layer 3: rotating duty wave, lane = block element, exact h-chain ----
        if (wq == (t & 7)) {
            unsigned int q0 = s2buf[slot][0][lane], q1 = s2buf[slot][1][lane];
            unsigned int q2 = s2buf[slot][2][lane], q3 = s2buf[slot][3][lane];
            unsigned int q4 = s2buf[slot][4][lane], q5 = s2buf[slot][5][lane];
            unsigned int q6 = s2buf[slot][6][lane], q7 = s2buf[slot][7][lane];
            ull s2v = (ull)(q0 | (q1 << 8) | (q2 << 16) | (q3 << 24))
                    | ((ull)(q4 | (q5 << 8) | (q6 << 16) | (q7 << 24)) << 32);
            float m3[A_OUT], ac[A_OUT];
            #pragma unroll
            for (int a = 0; a < A_OUT; ++a) { m3[a] = 0.95f * m3acc[lane][a]; ac[a] = m3acc[lane][4 + a]; }
            for (int h = 0; h < H; ++h) {        // h ascending: exact chain order
                float s2f = (float)((unsigned)s2v & 1u);
                s2v >>= 1;
                const float4 w = *reinterpret_cast<const float4*>(W3T + h * A_OUT); // uniform 16B
                m3[0] = fmaf_(s2f, w.x, m3[0]);
                m3[1] = fmaf_(s2f, w.y, m3[1]);
                m3[2] = fmaf_(s2f, w.z, m3[2]);
                m3[3] = fmaf_(s2f, w.w, m3[3]);
            }
            int myPost = 0;
            #pragma unroll
            for (int a = 0; a < A_OUT; ++a) {
                float m = m3[a] + b3[a];
                bool sp = m > 1.0f;
                float s3f = sp ? 1.0f : 0.0f;
                m3[a] = m - s3f;
                ac[a] = ac[a] + s3f;
                int c = (int)__popcll(__ballot(sp));
                myPost = (lane == a) ? c : myPost;
            }
            if (lane < A_OUT) lds_post[t * A_OUT + lane] = myPost;
            if (t == T_STEPS - 1) {
                float r0 = ac[0] * 0.0625f, r1 = ac[1] * 0.0625f;
                float r2 = ac[2] * 0.0625f, r3 = ac[3] * 0.0625f;
                float mx = fmaxf(fmaxf(r0, r1), fmaxf(r2, r3));
                float e0 = expf(r0 - mx), e1 = expf(r1 - mx);
                float e2 = expf(r2 - mx), e3 = expf(r3 - mx);
                float s = ((e0 + e1) + e2) + e3;
                reinterpret_cast<float4*>(out)[blockIdx.x * EPB + lane] =
                    make_float4(e0 / s, e1 / s, e2 / s, e3 / s);
            } else {
                #pragma unroll
                for (int a = 0; a < A_OUT; ++a) { m3acc[lane][a] = m3[a]; m3acc[lane][4 + a] = ac[a]; }
            }
        }
    }

    __syncthreads();
    for (int i = threadIdx.x; i < T_STEPS * H; i += 512) atomicAdd(&g_pre[i], lds_pre[i]);
    if (threadIdx.x < T_STEPS * A_OUT) atomicAdd(&g_post[threadIdx.x], lds_post[threadIdx.x]);
}

// elig_t = 0.95*elig_{t-1} + (A_PLUS-A_MINUS) * outer(post_t, pre_t); exact counts/B.
__global__ void snn_elig(const int* __restrict__ g_pre, const int* __restrict__ g_post,
                         const float* __restrict__ elig0, float* __restrict__ out) {
#pragma clang fp contract(off)
    int i = threadIdx.x;                 // 256 = A_OUT * H
    int a = i >> 6, h = i & 63;
    float e = elig0[i];
    const float invB = 1.0f / 65536.0f;
    for (int t = 0; t < T_STEPS; ++t) {
        float pre  = (float)g_pre[t * H + h] * invB;
        float post = (float)g_post[t * A_OUT + a] * invB;
        e = 0.95f * e + (-0.002f) * (post * pre);
    }
    out[NB * A_OUT + i] = e;
}

extern "C" void kernel_launch(void* const* d_in, const int* in_sizes, int n_in,
                              void* d_out, int out_size, void* d_ws, size_t ws_size,
                              hipStream_t stream) {
    const float* x     = (const float*)d_in[0];
    const float* W1    = (const float*)d_in[1];
    const float* b1    = (const float*)d_in[2];
    const float* W2    = (const float*)d_in[3];
    const float* b2    = (const float*)d_in[4];
    const float* W3    = (const float*)d_in[5];
    const float* b3    = (const float*)d_in[6];
    const float* elig0 = (const float*)d_in[7];
    float* out = (float*)d_out;

    char* ws = (char*)d_ws;
    int*   g_pre  = (int*)(ws);                    // 1024 ints
    int*   g_post = (int*)(ws + 4096);             // 64 ints
    float* W2T    = (float*)(ws + 8192);           // 4096 floats
    float* W3T    = (float*)(ws + 8192 + 16384);   // 256 floats

    (void)hipMemsetAsync(ws, 0, 4096 + 256, stream);  // zero count accumulators every launch
    snn_prep<<<17, 256, 0, stream>>>(W2, W3, W2T, W3T);
    snn_main<<<NB / EPB, 512, 0, stream>>>(x, W1, b1, W2T, b2, W3T, b3, out, g_pre, g_post);
    snn_elig<<<1, 256, 0, stream>>>(g_pre, g_post, elig0, out);
}

// Round 9
// 184.865 us; speedup vs baseline: 2.7285x; 1.0049x over previous
//
#include <hip/hip_runtime.h>

#define T_STEPS 16
#define H 64
#define S_IN 25
#define A_OUT 4
#define NB 65536
#define UPW 8             // units per thread (H / 8 waves)
#define WPB 8             // waves per block
#define EPB 64            // batch elements per block (one per lane)

typedef unsigned long long ull;

__device__ __forceinline__ float fmaf_(float a, float b, float c) { return __builtin_fmaf(a, b, c); }

// Transpose W2 (64x64) and W3 (4x64) into workspace so the hot loop reads
// contiguous wave-uniform rows (scalar s_load path, K$-cached).
__global__ void snn_prep(const float* __restrict__ W2, const float* __restrict__ W3,
                         float* __restrict__ W2T, float* __restrict__ W3T) {
    int i = blockIdx.x * blockDim.x + threadIdx.x;
    if (i < H * H) { int h = i >> 6, k = i & 63; W2T[k * H + h] = W2[h * H + k]; }
    if (i < A_OUT * H) { int a = i >> 6, h = i & 63; W3T[h * A_OUT + a] = W3[a * H + h]; }
}

// R8 structure (8 waves/SIMD, lane = batch element, weights via s_load) with
// the mask machinery replaced by f32 spike values in LDS: L2's per-k select is
// one ds_read_b32 at a static offset (LDS pipe) instead of ~3 VALU extract ops.
__global__ __launch_bounds__(512, 8) void snn_main(
    const float* __restrict__ x,
    const float* __restrict__ W1, const float* __restrict__ b1,
    const float* __restrict__ W2T, const float* __restrict__ b2,
    const float* __restrict__ W3T, const float* __restrict__ b3,
    float* __restrict__ out, int* __restrict__ g_pre, int* __restrict__ g_post)
{
#pragma clang fp contract(off)
    __shared__ float s1f[2][H][EPB];            // layer-1 spikes as 0.0/1.0 floats (32 KB)
    __shared__ unsigned char s2b[2][EPB][WPB];  // s2 masks, byte per wave, ull per elem
    __shared__ float m3acc[EPB][8];             // [elem][0..3]=m3, [4..7]=acc
    __shared__ int lds_pre[T_STEPS * H];
    __shared__ int lds_post[T_STEPS * A_OUT];

    for (int i = threadIdx.x; i < T_STEPS * H; i += 512) lds_pre[i] = 0;
    if (threadIdx.x < T_STEPS * A_OUT) lds_post[threadIdx.x] = 0;
    if (threadIdx.x < EPB * 8) (&m3acc[0][0])[threadIdx.x] = 0.0f;

    const int lane  = threadIdx.x & 63;
    const int wq    = __builtin_amdgcn_readfirstlane(threadIdx.x >> 6);  // wave 0..7 (SGPR)
    const int hbase = UPW * wq;                                          // this wave's unit range
    const int b     = blockIdx.x * EPB + lane;                           // batch element

    // cur1 for this thread's 8 units (same s-chain as reference)
    float cur1[UPW];
    {
        float xv[S_IN];
        #pragma unroll
        for (int s = 0; s < S_IN; ++s) xv[s] = x[b * S_IN + s];
        #pragma unroll
        for (int j = 0; j < UPW; ++j) {
            int h = hbase + j;                  // wave-uniform -> W1 row via s_load
            float acc = 0.0f;
            #pragma unroll
            for (int s = 0; s < S_IN; ++s) acc = fmaf_(xv[s], W1[h * S_IN + s], acc);
            cur1[j] = acc + b1[h];
        }
    }

    float m1[UPW], m2[UPW];
    #pragma unroll
    for (int j = 0; j < UPW; ++j) { m1[j] = 0.0f; m2[j] = 0.0f; }

    // ---- prologue: layer-1 at t=0, spikes as floats straight to LDS ----
    #pragma unroll
    for (int j = 0; j < UPW; ++j) {
        float m = 0.95f * m1[j];
        m = m + cur1[j];
        bool sp = m > 1.0f;
        m1[j] = sp ? (m - 1.0f) : m;
        s1f[0][hbase + j][lane] = sp ? 1.0f : 0.0f;
    }
    __syncthreads();

    for (int t = 0; t < T_STEPS; ++t) {
        const int slot = t & 1;

        // ---- layer 2: exact ascending-k chain; sf via ds_read (static offsets),
        //      weights via wave-uniform s_load (K$). 8 FMA + 1 LDS op per k.
        #pragma unroll
        for (int j = 0; j < UPW; ++j) m2[j] = 0.95f * m2[j];

        #pragma unroll 16
        for (int k = 0; k < H; ++k) {
            const float sf = s1f[slot][k][lane];          // ds_read_b32, offset k*256
            const float* wr = W2T + k * H + hbase;        // s_load_dwordx8 (uniform)
            #pragma unroll
            for (int j = 0; j < UPW; ++j) m2[j] = fmaf_(sf, wr[j], m2[j]);  // exact
        }

        // ---- layer-2 spikes + pre-counts (this wave's 8 units, all 64 elems) ----
        unsigned int s2loc = 0u;
        int myCnt = 0;
        #pragma unroll
        for (int j = 0; j < UPW; ++j) {
            float m = m2[j] + b2[hbase + j];
            bool sp = m > 1.0f;
            float s2f = sp ? 1.0f : 0.0f;
            m2[j] = m - s2f;
            s2loc |= (sp ? 1u : 0u) << j;
            int cnt = (int)__popcll(__ballot(sp));
            myCnt = (lane == j) ? cnt : myCnt;
        }
        s2b[slot][lane][wq] = (unsigned char)s2loc;
        if (lane < UPW) lds_pre[t * H + hbase + lane] = myCnt;  // single writer per h

        // ---- layer 1 for t+1 (independent of layer 3) ----
        if (t < T_STEPS - 1) {
            #pragma unroll
            for (int j = 0; j < UPW; ++j) {
                float m = 0.95f * m1[j];
                m = m + cur1[j];
                bool sp = m > 1.0f;
                m1[j] = sp ? (m - 1.0f) : m;
                s1f[slot ^ 1][hbase + j][lane] = sp ? 1.0f : 0.0f;
            }
        }
        __syncthreads();

        // ---- layer 3: rotating duty wave, lane = block element, exact h-chain ----
        if (wq == (t & 7)) {
            ull s2v = *reinterpret_cast<const ull*>(&s2b[slot][lane][0]);  // ds_read_b64
            float m3[A_OUT], ac[A_OUT];
            #pragma unroll
            for (int a = 0; a < A_OUT; ++a) { m3[a] = 0.95f * m3acc[lane][a]; ac[a] = m3acc[lane][4 + a]; }
            for (int h = 0; h < H; ++h) {        // h ascending: exact chain order
                float s2f = (float)((unsigned)s2v & 1u);
                s2v >>= 1;
                const float4 w = *reinterpret_cast<const float4*>(W3T + h * A_OUT); // uniform 16B
                m3[0] = fmaf_(s2f, w.x, m3[0]);
                m3[1] = fmaf_(s2f, w.y, m3[1]);
                m3[2] = fmaf_(s2f, w.z, m3[2]);
                m3[3] = fmaf_(s2f, w.w, m3[3]);
            }
            int myPost = 0;
            #pragma unroll
            for (int a = 0; a < A_OUT; ++a) {
                float m = m3[a] + b3[a];
                bool sp = m > 1.0f;
                float s3f = sp ? 1.0f : 0.0f;
                m3[a] = m - s3f;
                ac[a] = ac[a] + s3f;
                int c = (int)__popcll(__ballot(sp));
                myPost = (lane == a) ? c : myPost;
            }
            if (lane < A_OUT) lds_post[t * A_OUT + lane] = myPost;
            if (t == T_STEPS - 1) {
                float r0 = ac[0] * 0.0625f, r1 = ac[1] * 0.0625f;
                float r2 = ac[2] * 0.0625f, r3 = ac[3] * 0.0625f;
                float mx = fmaxf(fmaxf(r0, r1), fmaxf(r2, r3));
                float e0 = expf(r0 - mx), e1 = expf(r1 - mx);
                float e2 = expf(r2 - mx), e3 = expf(r3 - mx);
                float s = ((e0 + e1) + e2) + e3;
                reinterpret_cast<float4*>(out)[blockIdx.x * EPB + lane] =
                    make_float4(e0 / s, e1 / s, e2 / s, e3 / s);
            } else {
                #pragma unroll
                for (int a = 0; a < A_OUT; ++a) { m3acc[lane][a] = m3[a]; m3acc[lane][4 + a] = ac[a]; }
            }
        }
    }

    __syncthreads();
    for (int i = threadIdx.x; i < T_STEPS * H; i += 512) atomicAdd(&g_pre[i], lds_pre[i]);
    if (threadIdx.x < T_STEPS * A_OUT) atomicAdd(&g_post[threadIdx.x], lds_post[threadIdx.x]);
}

// elig_t = 0.95*elig_{t-1} + (A_PLUS-A_MINUS) * outer(post_t, pre_t); exact counts/B.
__global__ void snn_elig(const int* __restrict__ g_pre, const int* __restrict__ g_post,
                         const float* __restrict__ elig0, float* __restrict__ out) {
#pragma clang fp contract(off)
    int i = threadIdx.x;                 // 256 = A_OUT * H
    int a = i >> 6, h = i & 63;
    float e = elig0[i];
    const float invB = 1.0f / 65536.0f;
    for (int t = 0; t < T_STEPS; ++t) {
        float pre  = (float)g_pre[t * H + h] * invB;
        float post = (float)g_post[t * A_OUT + a] * invB;
        e = 0.95f * e + (-0.002f) * (post * pre);
    }
    out[NB * A_OUT + i] = e;
}

extern "C" void kernel_launch(void* const* d_in, const int* in_sizes, int n_in,
                              void* d_out, int out_size, void* d_ws, size_t ws_size,
                              hipStream_t stream) {
    const float* x     = (const float*)d_in[0];
    const float* W1    = (const float*)d_in[1];
    const float* b1    = (const float*)d_in[2];
    const float* W2    = (const float*)d_in[3];
    const float* b2    = (const float*)d_in[4];
    const float* W3    = (const float*)d_in[5];
    const float* b3    = (const float*)d_in[6];
    const float* elig0 = (const float*)d_in[7];
    float* out = (float*)d_out;

    char* ws = (char*)d_ws;
    int*   g_pre  = (int*)(ws);                    // 1024 ints
    int*   g_post = (int*)(ws + 4096);             // 64 ints
    float* W2T    = (float*)(ws + 8192);           // 4096 floats
    float* W3T    = (float*)(ws + 8192 + 16384);   // 256 floats

    (void)hipMemsetAsync(ws, 0, 4096 + 256, stream);  // zero count accumulators every launch
    snn_prep<<<17, 256, 0, stream>>>(W2, W3, W2T, W3T);
    snn_main<<<NB / EPB, 512, 0, stream>>>(x, W1, b1, W2T, b2, W3T, b3, out, g_pre, g_post);
    snn_elig<<<1, 256, 0, stream>>>(g_pre, g_post, elig0, out);
}